// Round 17
// baseline (68.843 us; speedup 1.0000x reference)
//
#include <hip/hip_runtime.h>
#include <hip/hip_bf16.h>

// Problem constants (from reference)
#define BB   16
#define NS   1024
#define NT   4096
#define CIN  256
#define CSK  64
#define HD   256           // hidden dim / output cols
#define K1   (CIN + CSK)   // 320
#define MTOT (BB * NT)     // 65536

typedef __attribute__((ext_vector_type(4))) float f32x4;
typedef __attribute__((ext_vector_type(8))) __bf16 bf16x8;
typedef __attribute__((ext_vector_type(4))) unsigned short ushort4v;

// ws layout (bytes)
#define W1F_OFF 0u                    // bf16[320*256]    = 163840
#define W2F_OFF 163840u               // bf16[256*256]    = 131072

static __device__ __forceinline__ unsigned short f2bf(float f) {
    union { float f; unsigned int u; } v; v.f = f;
    unsigned int r = (v.u + 0x7FFFu + ((v.u >> 16) & 1u)) >> 16;
    return (unsigned short)r;
}
// HW bf16 convert (RNE — bit-identical to f2bf on finite)
static __device__ __forceinline__ unsigned short f2bf_hw(float f) {
    union { __bf16 b; unsigned short u; } v; v.b = (__bf16)f;
    return v.u;
}

// ---- prep: W1/W2 swizzle into MFMA B-fragment order + out tail section ----
// Wf layout: Wf[kblk][n(16)][lane(64)][8]
//   k = kblk*32 + (lane>>4)*8 + j ; col = n*16 + (lane&15)
#define PREP_B1 (K1 * HD / 256)         // 320 blocks for W1f
#define PREP_B2 (HD * HD / 256)         // 256 blocks for W2f
#define PREP_B3 ((MTOT * 3) / 256)      // 768 blocks for tail
__global__ __launch_bounds__(256) void prep_kernel(
    const float* __restrict__ W1, const float* __restrict__ W2,
    const float* __restrict__ pos_skip,
    unsigned short* __restrict__ W1f, unsigned short* __restrict__ W2f,
    float* __restrict__ out)
{
    const int b = blockIdx.x;
    if (b < PREP_B1 + PREP_B2) {
        const bool is1 = b < PREP_B1;
        const int id = (is1 ? b : b - PREP_B1) * 256 + threadIdx.x;
        const int j    = id & 7;
        const int lane = (id >> 3) & 63;
        const int n    = (id >> 9) & 15;
        const int kblk = id >> 13;
        const int k   = kblk * 32 + (lane >> 4) * 8 + j;
        const int col = n * 16 + (lane & 15);
        if (is1) W1f[id] = f2bf(W1[(size_t)k * HD + col]);
        else     W2f[id] = f2bf(W2[(size_t)k * HD + col]);
    } else {
        const int i = (b - PREP_B1 - PREP_B2) * 256 + threadIdx.x;
        const size_t o1 = (size_t)MTOT * HD;
        out[o1 + i] = pos_skip[i];                                  // i < MTOT*3
        if (i < MTOT) out[o1 + (size_t)MTOT * 3 + i] = (float)(i >> 12);
    }
}

// ===== MEGAKERNEL (512 threads): kNN + gather + GEMM1 + GEMM2 per 64 rows =====
// 8 waves/block, 40 KB LDS -> 4 blocks/CU = 32 waves/CU (HW max). Same proven
// r13 phase structure and math; work re-split: kNN P=8 (128 cand/lane), gather
// 8 rows/wave, GEMM 2 N-frags/wave (acc[4][2]). B streams L2->VGPR; 5 barriers.
__global__ __launch_bounds__(512, 8) void fp_fused_kernel(
    const float* __restrict__ x, const float* __restrict__ x_skip,
    const float* __restrict__ pos, const float* __restrict__ pos_skip,
    const unsigned short* __restrict__ W1f, const unsigned short* __restrict__ W2f,
    const float* __restrict__ b1, const float* __restrict__ b2,
    float* __restrict__ out)
{
    __shared__ __align__(16) unsigned short ldsA[10 * 4 * 512]; // 40 KB exactly

    const int tid = threadIdx.x;
    const int w = tid >> 6, lane = tid & 63;   // w in [0,8)
    const int l15 = lane & 15, lk = lane >> 4;

    // cloud<->XCD affinity (bijective on [0,1024))
    const int bid   = blockIdx.x;
    const int xcd   = bid & 7;
    const int j     = bid >> 3;                 // 0..127
    const int cloud = xcd + 8 * (j >> 6);       // 0..15
    const int bm    = cloud * 64 + (j & 63);    // 64-row block index

    // B source pointers; prefetch GEMM1's first 2 B-frags before kNN
    const unsigned short* w1p = W1f + (w * 2) * 512 + lane * 8;
    const unsigned short* w2p = W2f + (w * 2) * 512 + lane * 8;
    bf16x8 bpre[2];
    #pragma unroll
    for (int nf = 0; nf < 2; ++nf)
        bpre[nf] = *(const bf16x8*)(w1p + nf * 512);

    // ---------------- phase 1: kNN for this block's 64 queries ----------------
    // Query q = tid>>3, partition p = tid&7. r13-proven f64 fma lex key.
    int   myi0, myi1, myi2;
    float myw0, myw1, myw2;
    {
        float4* sp = (float4*)ldsA;             // 16 KB overlay, dead after phase 1
        const float* pc = pos + (size_t)cloud * NS * 3;
        for (int i = tid; i < NS; i += 512)
            sp[i] = make_float4(pc[i * 3 + 0], pc[i * 3 + 1], pc[i * 3 + 2], 0.f);
        __syncthreads();                                            // [1]

        const int p  = tid & 7;
        const int rg = bm * 64 + (tid >> 3);
        const float qx = pos_skip[rg * 3 + 0];
        const float qy = pos_skip[rg * 3 + 1];
        const float qz = pos_skip[rg * 3 + 2];

        double b0 = 1e300, b1k = 1e300, b2k = 1e300;
        double si = (double)p;
        #pragma unroll 4
        for (int i = 0; i < NS / 8; ++i) {
            const int s = i * 8 + p;
            float4 c = sp[s];
            float dx = qx - c.x, dy = qy - c.y, dz = qz - c.z;
            float d = dx * dx + dy * dy + dz * dz;
            double key = fma((double)__float_as_uint(d), 1024.0, si);
            si += 8.0;
            double nb0 = fmin(b0, key);
            double nb1 = fmax(b0, fmin(b1k, key));
            double nb2 = fmax(b1k, fmin(b2k, key));
            b0 = nb0; b1k = nb1; b2k = nb2;
        }
        #pragma unroll
        for (int m = 1; m <= 4; m <<= 1) {
            double o0 = __shfl_xor(b0, m, 64);
            double o1 = __shfl_xor(b1k, m, 64);
            double o2 = __shfl_xor(b2k, m, 64);
            double nb0, nb1, nb2;
            nb0 = fmin(b0, o0); nb1 = fmax(b0, fmin(b1k, o0)); nb2 = fmax(b1k, fmin(b2k, o0));
            b0 = nb0; b1k = nb1; b2k = nb2;
            nb0 = fmin(b0, o1); nb1 = fmax(b0, fmin(b1k, o1)); nb2 = fmax(b1k, fmin(b2k, o1));
            b0 = nb0; b1k = nb1; b2k = nb2;
            nb0 = fmin(b0, o2); nb1 = fmax(b0, fmin(b1k, o2)); nb2 = fmax(b1k, fmin(b2k, o2));
            b0 = nb0; b1k = nb1; b2k = nb2;
        }
        // all 8 lanes of the group hold the merged triple -> decode everywhere
        unsigned long long k0 = (unsigned long long)b0;
        unsigned long long k1 = (unsigned long long)b1k;
        unsigned long long k2 = (unsigned long long)b2k;
        myi0 = (int)(k0 & 1023ull);
        myi1 = (int)(k1 & 1023ull);
        myi2 = (int)(k2 & 1023ull);
        float d0 = __uint_as_float((unsigned int)(k0 >> 10));
        float d1 = __uint_as_float((unsigned int)(k1 >> 10));
        float d2 = __uint_as_float((unsigned int)(k2 >> 10));
        float w0 = 1.f / fmaxf(d0, 1e-16f);
        float w1 = 1.f / fmaxf(d1, 1e-16f);
        float w2 = 1.f / fmaxf(d2, 1e-16f);
        float inv = 1.f / (w0 + w1 + w2);
        myw0 = w0 * inv; myw1 = w1 * inv; myw2 = w2 * inv;
        __syncthreads();   // [2] sp reads complete (ldsA about to be overwritten)
    }

    // ------- phase 2: one-shot A gather/blend (all 320 cols -> ldsA) -------
    // Wave w gathers rows w*8..w*8+7; row (w*8+r8)'s kNN owner thread is
    // (w*8+r8)*8 = wave w, lane r8*8 -> intra-wave shfl (readlane).
    {
        const int cb  = cloud * NS;             // cloud base row in x
        const int kbm = lane >> 3;              // main: c=4*lane -> kb (0..7)
        const int lkm = (lane >> 1) & 3;
        const int em  = lane & 1;
        const int kbs = 8 + (lane >> 5);        // skip: c=256+lane -> kb (8,9)
        const int lks = (lane >> 3) & 3;
        const int jjs = lane & 7;
        #pragma unroll
        for (int r8 = 0; r8 < 8; ++r8) {
            const int src = r8 * 8;
            const int i0 = cb + __shfl(myi0, src, 64);
            const int i1 = cb + __shfl(myi1, src, 64);
            const int i2 = cb + __shfl(myi2, src, 64);
            const float w0 = __shfl(myw0, src, 64);
            const float w1 = __shfl(myw1, src, 64);
            const float w2 = __shfl(myw2, src, 64);
            const int row = w * 8 + r8;         // 0..63
            const int rg  = bm * 64 + row;
            const int mfr = row >> 4;           // 0..3
            const int r15 = row & 15;
            f32x4 a = *(const f32x4*)(x + (size_t)i0 * CIN + lane * 4);
            f32x4 b = *(const f32x4*)(x + (size_t)i1 * CIN + lane * 4);
            f32x4 c = *(const f32x4*)(x + (size_t)i2 * CIN + lane * 4);
            float s = x_skip[(size_t)rg * CSK + lane];
            f32x4 r = a * w0 + b * w1 + c * w2;
            int H = ((kbm * 4 + mfr) * 64 + (r15 + 16 * lkm)) * 8 + 4 * em;
            H ^= (kbm & 7) << 3;
            ushort4v o4 = { f2bf_hw(r[0]), f2bf_hw(r[1]), f2bf_hw(r[2]), f2bf_hw(r[3]) };
            *(ushort4v*)&ldsA[H] = o4;
            int H2 = ((kbs * 4 + mfr) * 64 + (r15 + 16 * lks)) * 8 + jjs;
            H2 ^= (kbs & 7) << 3;
            ldsA[H2] = f2bf_hw(s);
        }
    }
    __syncthreads();   // [3] A tile complete

    // ---------------- phase 3: GEMM1 k-loop, barrier-free (B: L2->VGPR) ----------------
    // Wave w owns N-frags {2w, 2w+1}; acc[4][2].
    f32x4 acc[4][2];
    #pragma unroll
    for (int mf = 0; mf < 4; ++mf)
        #pragma unroll
        for (int nf = 0; nf < 2; ++nf)
            acc[mf][nf] = f32x4{0.f, 0.f, 0.f, 0.f};

    {
        bf16x8 bc[2], bn[2];
        #pragma unroll
        for (int nf = 0; nf < 2; ++nf) bc[nf] = bpre[nf];
        #pragma unroll
        for (int kb = 0; kb < 10; ++kb) {
            if (kb < 9) {
                #pragma unroll
                for (int nf = 0; nf < 2; ++nf)
                    bn[nf] = *(const bf16x8*)(w1p + (size_t)(kb + 1) * 8192 + nf * 512);
            }
            bf16x8 a[4];
            #pragma unroll
            for (int mf = 0; mf < 4; ++mf) {
                int aoff = ((kb * 4 + mf) * 64 + lane) * 8;
                aoff ^= (kb & 7) << 3;
                a[mf] = *(const bf16x8*)&ldsA[aoff];
            }
            #pragma unroll
            for (int mf = 0; mf < 4; ++mf)
                #pragma unroll
                for (int nf = 0; nf < 2; ++nf)
                    acc[mf][nf] = __builtin_amdgcn_mfma_f32_16x16x32_bf16(
                        a[mf], bc[nf], acc[mf][nf], 0, 0, 0);
            #pragma unroll
            for (int nf = 0; nf < 2; ++nf) bc[nf] = bn[nf];
        }
    }
    __syncthreads();   // [4] all ldsA reads done; safe to overwrite with h1

    // ------- phase 4: h1 = relu(acc + b1) -> bf16 -> ldsA in A-frag layout -------
    // elem (row = mf*16+lk*4+r, col = w*32+nf*16+l15):
    //   kb2 = col>>5 = w; slot = (lk*4+r) + 16*(nf*2 + (l15>>3)); j = l15&7
    #pragma unroll
    for (int nf = 0; nf < 2; ++nf) {
        const int col = w * 32 + nf * 16 + l15;
        const float bv = b1[col];
        const int soff = 16 * (nf * 2 + (l15 >> 3)) + lk * 4;
        #pragma unroll
        for (int mf = 0; mf < 4; ++mf) {
            #pragma unroll
            for (int r = 0; r < 4; ++r) {
                float v = fmaxf(acc[mf][nf][r] + bv, 0.f);
                ldsA[((w * 4 + mf) * 64 + soff + r) * 8 + (l15 & 7)] = f2bf_hw(v);
            }
        }
    }
    __syncthreads();   // [5] h1 tile complete

    // ---------------- phase 5: GEMM2 k-loop, barrier-free ----------------
    f32x4 acc2[4][2];
    #pragma unroll
    for (int mf = 0; mf < 4; ++mf)
        #pragma unroll
        for (int nf = 0; nf < 2; ++nf)
            acc2[mf][nf] = f32x4{0.f, 0.f, 0.f, 0.f};

    {
        bf16x8 bc[2], bn[2];
        #pragma unroll
        for (int nf = 0; nf < 2; ++nf)
            bc[nf] = *(const bf16x8*)(w2p + nf * 512);
        #pragma unroll
        for (int kb = 0; kb < 8; ++kb) {
            if (kb < 7) {
                #pragma unroll
                for (int nf = 0; nf < 2; ++nf)
                    bn[nf] = *(const bf16x8*)(w2p + (size_t)(kb + 1) * 8192 + nf * 512);
            }
            bf16x8 a[4];
            #pragma unroll
            for (int mf = 0; mf < 4; ++mf)
                a[mf] = *(const bf16x8*)&ldsA[((kb * 4 + mf) * 64 + lane) * 8];
            #pragma unroll
            for (int mf = 0; mf < 4; ++mf)
                #pragma unroll
                for (int nf = 0; nf < 2; ++nf)
                    acc2[mf][nf] = __builtin_amdgcn_mfma_f32_16x16x32_bf16(
                        a[mf], bc[nf], acc2[mf][nf], 0, 0, 0);
            #pragma unroll
            for (int nf = 0; nf < 2; ++nf) bc[nf] = bn[nf];
        }
    }

    // epilogue: out = relu(acc2 + b2), f32
    const int rbase = bm * 64 + lk * 4;
    const int cbase = w * 32 + l15;
    #pragma unroll
    for (int nf = 0; nf < 2; ++nf) {
        const int col = cbase + nf * 16;
        const float bv = b2[col];
        #pragma unroll
        for (int mf = 0; mf < 4; ++mf) {
            #pragma unroll
            for (int r = 0; r < 4; ++r) {
                float v = fmaxf(acc2[mf][nf][r] + bv, 0.f);
                out[(size_t)(rbase + mf * 16 + r) * HD + col] = v;
            }
        }
    }
}

extern "C" void kernel_launch(void* const* d_in, const int* in_sizes, int n_in,
                              void* d_out, int out_size, void* d_ws, size_t ws_size,
                              hipStream_t stream)
{
    const float* x        = (const float*)d_in[0];
    const float* pos      = (const float*)d_in[1];
    const float* x_skip   = (const float*)d_in[2];
    const float* pos_skip = (const float*)d_in[3];
    const float* W1       = (const float*)d_in[4];
    const float* b1       = (const float*)d_in[5];
    const float* W2       = (const float*)d_in[6];
    const float* b2       = (const float*)d_in[7];
    float* out = (float*)d_out;

    char* ws = (char*)d_ws;
    unsigned short* W1f  = (unsigned short*)(ws + W1F_OFF);
    unsigned short* W2f  = (unsigned short*)(ws + W2F_OFF);

    prep_kernel<<<PREP_B1 + PREP_B2 + PREP_B3, 256, 0, stream>>>(
        W1, W2, pos_skip, W1f, W2f, out);
    fp_fused_kernel<<<MTOT / 64, 512, 0, stream>>>(
        x, x_skip, pos, pos_skip, W1f, W2f, b1, b2, out);
}

// Round 18
// 62.750 us; speedup vs baseline: 1.0971x; 1.0971x over previous
//
#include <hip/hip_runtime.h>
#include <hip/hip_bf16.h>

// Problem constants (from reference)
#define BB   16
#define NS   1024
#define NT   4096
#define CIN  256
#define CSK  64
#define HD   256           // hidden dim / output cols
#define K1   (CIN + CSK)   // 320
#define MTOT (BB * NT)     // 65536

typedef __attribute__((ext_vector_type(4))) float f32x4;
typedef __attribute__((ext_vector_type(8))) __bf16 bf16x8;
typedef __attribute__((ext_vector_type(4))) unsigned short ushort4v;

// ws layout (bytes)
#define W1F_OFF 0u                    // bf16[320*256]    = 163840
#define W2F_OFF 163840u               // bf16[256*256]    = 131072

static __device__ __forceinline__ unsigned short f2bf(float f) {
    union { float f; unsigned int u; } v; v.f = f;
    unsigned int r = (v.u + 0x7FFFu + ((v.u >> 16) & 1u)) >> 16;
    return (unsigned short)r;
}
// HW bf16 convert (RNE — bit-identical to f2bf on finite)
static __device__ __forceinline__ unsigned short f2bf_hw(float f) {
    union { __bf16 b; unsigned short u; } v; v.b = (__bf16)f;
    return v.u;
}

// ---- prep: W1/W2 swizzle into MFMA B-fragment order + out tail section ----
// Wf layout: Wf[kblk][n(16)][lane(64)][8]
//   k = kblk*32 + (lane>>4)*8 + j ; col = n*16 + (lane&15)
#define PREP_B1 (K1 * HD / 256)         // 320 blocks for W1f
#define PREP_B2 (HD * HD / 256)         // 256 blocks for W2f
#define PREP_B3 ((MTOT * 3) / 256)      // 768 blocks for tail
__global__ __launch_bounds__(256) void prep_kernel(
    const float* __restrict__ W1, const float* __restrict__ W2,
    const float* __restrict__ pos_skip,
    unsigned short* __restrict__ W1f, unsigned short* __restrict__ W2f,
    float* __restrict__ out)
{
    const int b = blockIdx.x;
    if (b < PREP_B1 + PREP_B2) {
        const bool is1 = b < PREP_B1;
        const int id = (is1 ? b : b - PREP_B1) * 256 + threadIdx.x;
        const int j    = id & 7;
        const int lane = (id >> 3) & 63;
        const int n    = (id >> 9) & 15;
        const int kblk = id >> 13;
        const int k   = kblk * 32 + (lane >> 4) * 8 + j;
        const int col = n * 16 + (lane & 15);
        if (is1) W1f[id] = f2bf(W1[(size_t)k * HD + col]);
        else     W2f[id] = f2bf(W2[(size_t)k * HD + col]);
    } else {
        const int i = (b - PREP_B1 - PREP_B2) * 256 + threadIdx.x;
        const size_t o1 = (size_t)MTOT * HD;
        out[o1 + i] = pos_skip[i];                                  // i < MTOT*3
        if (i < MTOT) out[o1 + (size_t)MTOT * 3 + i] = (float)(i >> 12);
    }
}

// ===== MEGAKERNEL: kNN + interp-gather + GEMM1 + GEMM2 per 64-row block =====
// Barrier-minimal (5 barriers). B operands stream L2->VGPR (no ldsB).
// ldsA = exactly 40960 B (no sidx/swgt: kNN results broadcast via readlane,
// gather row-bases become SGPR-uniform) -> 4 blocks/CU (4*40960 = 160 KB).
__global__ __launch_bounds__(256, 4) void fp_fused_kernel(
    const float* __restrict__ x, const float* __restrict__ x_skip,
    const float* __restrict__ pos, const float* __restrict__ pos_skip,
    const unsigned short* __restrict__ W1f, const unsigned short* __restrict__ W2f,
    const float* __restrict__ b1, const float* __restrict__ b2,
    float* __restrict__ out)
{
    __shared__ __align__(16) unsigned short ldsA[10 * 4 * 512]; // 40 KB exactly

    const int tid = threadIdx.x;
    const int w = tid >> 6, lane = tid & 63;
    const int l15 = lane & 15, lk = lane >> 4;

    // cloud<->XCD affinity (bijective on [0,1024))
    const int bid   = blockIdx.x;
    const int xcd   = bid & 7;
    const int j     = bid >> 3;                 // 0..127
    const int cloud = xcd + 8 * (j >> 6);       // 0..15
    const int bm    = cloud * 64 + (j & 63);    // 64-row block index

    // ---------------- phase 1: kNN for this block's 64 queries ----------------
    // Query q = tid>>2 (row of this block), partition p = tid&3.
    int   myi0, myi1, myi2;          // per-query results (all 4 lanes of group)
    float myw0, myw1, myw2;
    {
        float4* sp = (float4*)ldsA;             // 16 KB overlay, dead after phase 1
        const float* pc = pos + (size_t)cloud * NS * 3;
        for (int i = tid; i < NS; i += 256)
            sp[i] = make_float4(pc[i * 3 + 0], pc[i * 3 + 1], pc[i * 3 + 2], 0.f);
        __syncthreads();                                            // [1]

        const int p  = tid & 3;
        const int rg = bm * 64 + (tid >> 2);
        const float qx = pos_skip[rg * 3 + 0];
        const float qy = pos_skip[rg * 3 + 1];
        const float qz = pos_skip[rg * 3 + 2];

        double b0 = 1e300, b1k = 1e300, b2k = 1e300;
        double si = (double)p;
        #pragma unroll 4
        for (int i = 0; i < NS / 4; ++i) {
            const int s = i * 4 + p;
            float4 c = sp[s];
            float dx = qx - c.x, dy = qy - c.y, dz = qz - c.z;
            float d = dx * dx + dy * dy + dz * dz;
            double key = fma((double)__float_as_uint(d), 1024.0, si);
            si += 4.0;
            double nb0 = fmin(b0, key);
            double nb1 = fmax(b0, fmin(b1k, key));
            double nb2 = fmax(b1k, fmin(b2k, key));
            b0 = nb0; b1k = nb1; b2k = nb2;
        }
        #pragma unroll
        for (int m = 1; m <= 2; m <<= 1) {
            double o0 = __shfl_xor(b0, m, 64);
            double o1 = __shfl_xor(b1k, m, 64);
            double o2 = __shfl_xor(b2k, m, 64);
            double nb0, nb1, nb2;
            nb0 = fmin(b0, o0); nb1 = fmax(b0, fmin(b1k, o0)); nb2 = fmax(b1k, fmin(b2k, o0));
            b0 = nb0; b1k = nb1; b2k = nb2;
            nb0 = fmin(b0, o1); nb1 = fmax(b0, fmin(b1k, o1)); nb2 = fmax(b1k, fmin(b2k, o1));
            b0 = nb0; b1k = nb1; b2k = nb2;
            nb0 = fmin(b0, o2); nb1 = fmax(b0, fmin(b1k, o2)); nb2 = fmax(b1k, fmin(b2k, o2));
            b0 = nb0; b1k = nb1; b2k = nb2;
        }
        // all 4 lanes of the group hold the merged triple -> decode everywhere
        unsigned long long k0 = (unsigned long long)b0;
        unsigned long long k1 = (unsigned long long)b1k;
        unsigned long long k2 = (unsigned long long)b2k;
        myi0 = (int)(k0 & 1023ull);
        myi1 = (int)(k1 & 1023ull);
        myi2 = (int)(k2 & 1023ull);
        float d0 = __uint_as_float((unsigned int)(k0 >> 10));
        float d1 = __uint_as_float((unsigned int)(k1 >> 10));
        float d2 = __uint_as_float((unsigned int)(k2 >> 10));
        float w0 = 1.f / fmaxf(d0, 1e-16f);
        float w1 = 1.f / fmaxf(d1, 1e-16f);
        float w2 = 1.f / fmaxf(d2, 1e-16f);
        float inv = 1.f / (w0 + w1 + w2);
        myw0 = w0 * inv; myw1 = w1 * inv; myw2 = w2 * inv;
        __syncthreads();   // [2] sp reads complete (ldsA about to be overwritten)
    }

    // ------- phase 2: one-shot A gather/blend (all 320 cols -> ldsA) -------
    // Row w*16+r16's kNN result lives in lane 4*r16 of THIS wave: readlane ->
    // SGPR row-bases, uniform addressing.
    {
        const int cb  = cloud * NS;             // cloud base row in x
        const int kbm = lane >> 3;              // main: c=4*lane -> kb (0..7)
        const int lkm = (lane >> 1) & 3;
        const int em  = lane & 1;
        const int kbs = 8 + (lane >> 5);        // skip: c=256+lane -> kb (8,9)
        const int lks = (lane >> 3) & 3;
        const int jjs = lane & 7;
        #pragma unroll
        for (int r16 = 0; r16 < 16; ++r16) {
            const int src = r16 * 4;
            const int i0 = cb + __shfl(myi0, src, 64);
            const int i1 = cb + __shfl(myi1, src, 64);
            const int i2 = cb + __shfl(myi2, src, 64);
            const float w0 = __shfl(myw0, src, 64);
            const float w1 = __shfl(myw1, src, 64);
            const float w2 = __shfl(myw2, src, 64);
            const int row = w * 16 + r16;
            const int rg  = bm * 64 + row;
            f32x4 a = *(const f32x4*)(x + (size_t)i0 * CIN + lane * 4);
            f32x4 b = *(const f32x4*)(x + (size_t)i1 * CIN + lane * 4);
            f32x4 c = *(const f32x4*)(x + (size_t)i2 * CIN + lane * 4);
            float s = x_skip[(size_t)rg * CSK + lane];
            f32x4 r = a * w0 + b * w1 + c * w2;
            int H = ((kbm * 4 + w) * 64 + (r16 + 16 * lkm)) * 8 + 4 * em;
            H ^= (kbm & 7) << 3;
            ushort4v o4 = { f2bf_hw(r[0]), f2bf_hw(r[1]), f2bf_hw(r[2]), f2bf_hw(r[3]) };
            *(ushort4v*)&ldsA[H] = o4;
            int H2 = ((kbs * 4 + w) * 64 + (r16 + 16 * lks)) * 8 + jjs;
            H2 ^= (kbs & 7) << 3;
            ldsA[H2] = f2bf_hw(s);
        }
    }
    __syncthreads();   // [3] A tile complete

    // ---------------- phase 3: GEMM1 k-loop, barrier-free (B: L2->VGPR) ----------------
    const unsigned short* w1p = W1f + (w * 4) * 512 + lane * 8;
    const unsigned short* w2p = W2f + (w * 4) * 512 + lane * 8;

    f32x4 acc[4][4];
    #pragma unroll
    for (int mf = 0; mf < 4; ++mf)
        #pragma unroll
        for (int nf = 0; nf < 4; ++nf)
            acc[mf][nf] = f32x4{0.f, 0.f, 0.f, 0.f};

    {
        bf16x8 bc[4], bn[4];
        #pragma unroll
        for (int nf = 0; nf < 4; ++nf)
            bc[nf] = *(const bf16x8*)(w1p + nf * 512);
        #pragma unroll
        for (int kb = 0; kb < 10; ++kb) {
            if (kb < 9) {
                #pragma unroll
                for (int nf = 0; nf < 4; ++nf)
                    bn[nf] = *(const bf16x8*)(w1p + (size_t)(kb + 1) * 8192 + nf * 512);
            }
            bf16x8 a[4];
            #pragma unroll
            for (int mf = 0; mf < 4; ++mf) {
                int aoff = ((kb * 4 + mf) * 64 + lane) * 8;
                aoff ^= (kb & 7) << 3;
                a[mf] = *(const bf16x8*)&ldsA[aoff];
            }
            #pragma unroll
            for (int mf = 0; mf < 4; ++mf)
                #pragma unroll
                for (int nf = 0; nf < 4; ++nf)
                    acc[mf][nf] = __builtin_amdgcn_mfma_f32_16x16x32_bf16(
                        a[mf], bc[nf], acc[mf][nf], 0, 0, 0);
            #pragma unroll
            for (int nf = 0; nf < 4; ++nf) bc[nf] = bn[nf];
        }
    }
    __syncthreads();   // [4] all ldsA reads done; safe to overwrite with h1

    // ------- phase 4: h1 = relu(acc + b1) -> bf16 -> ldsA in A-frag layout -------
    // elem (row=mf*16+lk*4+r, col=w*64+nf*16+l15):
    //   kb2 = 2w + (nf>>1); lane2 = lk*4+r + 16*((nf&1)*2 + (l15>>3)); j = l15&7
    #pragma unroll
    for (int nf = 0; nf < 4; ++nf) {
        const int col = w * 64 + nf * 16 + l15;
        const float bv = b1[col];
        const int kb2   = 2 * w + (nf >> 1);
        const int lane2 = lk * 4 + 16 * ((nf & 1) * 2 + (l15 >> 3));
        #pragma unroll
        for (int mf = 0; mf < 4; ++mf) {
            #pragma unroll
            for (int r = 0; r < 4; ++r) {
                float v = fmaxf(acc[mf][nf][r] + bv, 0.f);
                ldsA[((kb2 * 4 + mf) * 64 + lane2 + r) * 8 + (l15 & 7)] = f2bf_hw(v);
            }
        }
    }
    __syncthreads();   // [5] h1 tile complete

    // ---------------- phase 5: GEMM2 k-loop, barrier-free ----------------
    f32x4 acc2[4][4];
    #pragma unroll
    for (int mf = 0; mf < 4; ++mf)
        #pragma unroll
        for (int nf = 0; nf < 4; ++nf)
            acc2[mf][nf] = f32x4{0.f, 0.f, 0.f, 0.f};

    {
        bf16x8 bc[4], bn[4];
        #pragma unroll
        for (int nf = 0; nf < 4; ++nf)
            bc[nf] = *(const bf16x8*)(w2p + nf * 512);
        #pragma unroll
        for (int kb = 0; kb < 8; ++kb) {
            if (kb < 7) {
                #pragma unroll
                for (int nf = 0; nf < 4; ++nf)
                    bn[nf] = *(const bf16x8*)(w2p + (size_t)(kb + 1) * 8192 + nf * 512);
            }
            bf16x8 a[4];
            #pragma unroll
            for (int mf = 0; mf < 4; ++mf)
                a[mf] = *(const bf16x8*)&ldsA[((kb * 4 + mf) * 64 + lane) * 8];
            #pragma unroll
            for (int mf = 0; mf < 4; ++mf)
                #pragma unroll
                for (int nf = 0; nf < 4; ++nf)
                    acc2[mf][nf] = __builtin_amdgcn_mfma_f32_16x16x32_bf16(
                        a[mf], bc[nf], acc2[mf][nf], 0, 0, 0);
            #pragma unroll
            for (int nf = 0; nf < 4; ++nf) bc[nf] = bn[nf];
        }
    }

    // epilogue: out = relu(acc2 + b2), f32
    const int rbase = bm * 64 + lk * 4;
    const int cbase = w * 64 + l15;
    #pragma unroll
    for (int nf = 0; nf < 4; ++nf) {
        const int col = cbase + nf * 16;
        const float bv = b2[col];
        #pragma unroll
        for (int mf = 0; mf < 4; ++mf) {
            #pragma unroll
            for (int r = 0; r < 4; ++r) {
                float v = fmaxf(acc2[mf][nf][r] + bv, 0.f);
                out[(size_t)(rbase + mf * 16 + r) * HD + col] = v;
            }
        }
    }
}

extern "C" void kernel_launch(void* const* d_in, const int* in_sizes, int n_in,
                              void* d_out, int out_size, void* d_ws, size_t ws_size,
                              hipStream_t stream)
{
    const float* x        = (const float*)d_in[0];
    const float* pos      = (const float*)d_in[1];
    const float* x_skip   = (const float*)d_in[2];
    const float* pos_skip = (const float*)d_in[3];
    const float* W1       = (const float*)d_in[4];
    const float* b1       = (const float*)d_in[5];
    const float* W2       = (const float*)d_in[6];
    const float* b2       = (const float*)d_in[7];
    float* out = (float*)d_out;

    char* ws = (char*)d_ws;
    unsigned short* W1f  = (unsigned short*)(ws + W1F_OFF);
    unsigned short* W2f  = (unsigned short*)(ws + W2F_OFF);

    prep_kernel<<<PREP_B1 + PREP_B2 + PREP_B3, 256, 0, stream>>>(
        W1, W2, pos_skip, W1f, W2f, out);
    fp_fused_kernel<<<MTOT / 64, 256, 0, stream>>>(
        x, x_skip, pos, pos_skip, W1f, W2f, b1, b2, out);
}